// Round 1
// baseline (4182.298 us; speedup 1.0000x reference)
//
#include <hip/hip_runtime.h>
#include <hip/hip_bf16.h>
#include <stdint.h>

// Problem constants (fixed by the reference)
#define NN   50000
#define RR   50
#define BB   30
#define DIN  64
#define EE   1000000
#define KTOT (BB*DIN + DIN)   // 1984: 30 bases * 64 din + 64 root rows
#define NBW  8                // nodes per workgroup in fused kernel

// ---------------- preprocessing: counting sort of edges by dst ----------------

__global__ void k_hist(const int* __restrict__ dst, const int* __restrict__ et,
                       int* __restrict__ cnt, int* __restrict__ dcount) {
    int e = blockIdx.x * 256 + threadIdx.x;
    if (e < EE) {
        int d = dst[e], r = et[e];
        atomicAdd(&cnt[d * RR + r], 1);
        atomicAdd(&dcount[d], 1);
    }
}

__global__ void k_scan1(const int* __restrict__ dcount, int* __restrict__ doff,
                        int* __restrict__ bsum) {
    __shared__ int sh[256];
    int t = threadIdx.x;
    int i = blockIdx.x * 256 + t;
    int v = (i < NN) ? dcount[i] : 0;
    sh[t] = v;
    __syncthreads();
    for (int s = 1; s < 256; s <<= 1) {
        int add = (t >= s) ? sh[t - s] : 0;
        __syncthreads();
        sh[t] += add;
        __syncthreads();
    }
    int incl = sh[t];
    if (i < NN) doff[i] = incl - v;            // exclusive within block
    if (t == 255) bsum[blockIdx.x] = incl;     // block total
}

__global__ void k_scan2(int* __restrict__ bsum, int nbv) {
    __shared__ int sh[256];
    int t = threadIdx.x;
    int v = (t < nbv) ? bsum[t] : 0;
    sh[t] = v;
    __syncthreads();
    for (int s = 1; s < 256; s <<= 1) {
        int add = (t >= s) ? sh[t - s] : 0;
        __syncthreads();
        sh[t] += add;
        __syncthreads();
    }
    if (t < nbv) bsum[t] = sh[t] - v;          // exclusive block bases
}

__global__ void k_scan3(int* __restrict__ doff, const int* __restrict__ bsum) {
    int i = blockIdx.x * 256 + threadIdx.x;
    if (i < NN) doff[i] += bsum[blockIdx.x];
}

// pack each edge as {src, rel, alpha_bits, 0} so the fused kernel does one s_load_dwordx4
__global__ void k_scatter(const int* __restrict__ src, const int* __restrict__ dst,
                          const int* __restrict__ et, const int* __restrict__ cnt,
                          const int* __restrict__ doff, int* __restrict__ cursor,
                          int4* __restrict__ epack) {
    int e = blockIdx.x * 256 + threadIdx.x;
    if (e < EE) {
        int d = dst[e], r = et[e], s = src[e];
        int p = doff[d] + atomicAdd(&cursor[d], 1);
        float a = 1.0f / (float)cnt[d * RR + r];
        epack[p] = make_int4(s, r, __float_as_int(a), 0);
    }
}

__global__ void k_cast_x(const float* __restrict__ x, __hip_bfloat16* __restrict__ h) {
    int i = blockIdx.x * 256 + threadIdx.x;
    if (i < NN * DIN) h[i] = __float2bfloat16(x[i]);
}

// ---------------- fused per-layer kernel ----------------
// Phase 1: each wave owns one node; accumulates t[b][lane] (b=0..29) in regs,
//          plus the node's own x (root term) -> LDS t_tile[node][1984].
// Phase 2: all 256 threads: out[j][o] = sum_k t_tile[j][k] * W[k][o] (+bias),
//          where W rows 0..1919 = bases (flattened [b*64+i][o]), 1920..1983 = root.

template <int DOUT, bool RELU>
__global__ __launch_bounds__(256, 2)
void k_fused(const __hip_bfloat16* __restrict__ xin,
             const int4* __restrict__ epack,
             const int* __restrict__ doff, const int* __restrict__ dcount,
             const float* __restrict__ comp,     // [R, B]
             const float* __restrict__ bases,    // [B, DIN, DOUT] flat
             const float* __restrict__ root,     // [DIN, DOUT]
             const float* __restrict__ bias,     // [DOUT]
             void* __restrict__ outp) {
    __shared__ __align__(16) float t_tile[NBW][KTOT];   // 8*1984*4 = 63488 B
    const int tid  = threadIdx.x;
    const int lane = tid & 63;
    const int wv   = __builtin_amdgcn_readfirstlane(tid >> 6);   // wave id 0..3, force scalar
    const int node0 = blockIdx.x * NBW;

    // ---- phase 1 ----
    for (int jj = 0; jj < NBW / 4; ++jj) {
        int j = wv + jj * 4;
        int n = node0 + j;
        float acc[BB];
#pragma unroll
        for (int b = 0; b < BB; ++b) acc[b] = 0.f;
        float xself = 0.f;
        if (n < NN) {
            int beg  = doff[n];
            int cntn = dcount[n];
            for (int e = 0; e < cntn; ++e) {
                int4 ep = epack[beg + e];                 // wave-uniform -> s_load
                float a  = __int_as_float(ep.z);
                float xv = __bfloat162float(xin[ep.x * DIN + lane]) * a;
                const float* crow = comp + ep.y * BB;     // wave-uniform -> s_loads
#pragma unroll
                for (int b = 0; b < BB; ++b) acc[b] = fmaf(crow[b], xv, acc[b]);
            }
            xself = __bfloat162float(xin[n * DIN + lane]);
        }
#pragma unroll
        for (int b = 0; b < BB; ++b) t_tile[j][b * DIN + lane] = acc[b];
        t_tile[j][BB * DIN + lane] = xself;
    }
    __syncthreads();

    // ---- phase 2 ----
    constexpr int PT = (NBW * DOUT + 255) / 256;   // 2 for DOUT=64, 1 for DOUT=8
    const int o = tid % DOUT;
    float acc2[PT];
#pragma unroll
    for (int q = 0; q < PT; ++q) acc2[q] = 0.f;

    for (int k0 = 0; k0 < KTOT; k0 += 4) {
        const float* wrow = (k0 < BB * DIN) ? (bases + k0 * DOUT)
                                            : (root + (k0 - BB * DIN) * DOUT);
        float w0 = wrow[o];
        float w1 = wrow[DOUT + o];
        float w2 = wrow[2 * DOUT + o];
        float w3 = wrow[3 * DOUT + o];
#pragma unroll
        for (int q = 0; q < PT; ++q) {
            int out = tid + q * 256;
            if (out < NBW * DOUT) {
                int j = out / DOUT;
                const float4 t4 = *reinterpret_cast<const float4*>(&t_tile[j][k0]);
                float s = acc2[q];
                s = fmaf(t4.x, w0, s);
                s = fmaf(t4.y, w1, s);
                s = fmaf(t4.z, w2, s);
                s = fmaf(t4.w, w3, s);
                acc2[q] = s;
            }
        }
    }

#pragma unroll
    for (int q = 0; q < PT; ++q) {
        int out = tid + q * 256;
        if (out < NBW * DOUT) {
            int j = out / DOUT;
            int n = node0 + j;
            if (n < NN) {
                float v = acc2[q] + bias[o];
                if (RELU) {
                    v = fmaxf(v, 0.f);
                    reinterpret_cast<__hip_bfloat16*>(outp)[n * DOUT + o] = __float2bfloat16(v);
                } else {
                    reinterpret_cast<float*>(outp)[n * DOUT + o] = v;
                }
            }
        }
    }
}

// ---------------- log_softmax over C=8 ----------------
__global__ void k_lsm(const float* __restrict__ pre, float* __restrict__ out) {
    int n = blockIdx.x * 256 + threadIdx.x;
    if (n < NN) {
        float v[8];
        float m = -1e30f;
#pragma unroll
        for (int c = 0; c < 8; ++c) { v[c] = pre[n * 8 + c]; m = fmaxf(m, v[c]); }
        float s = 0.f;
#pragma unroll
        for (int c = 0; c < 8; ++c) s += expf(v[c] - m);
        float ls = logf(s);
#pragma unroll
        for (int c = 0; c < 8; ++c) out[n * 8 + c] = v[c] - m - ls;
    }
}

// ---------------- launch ----------------
extern "C" void kernel_launch(void* const* d_in, const int* in_sizes, int n_in,
                              void* d_out, int out_size, void* d_ws, size_t ws_size,
                              hipStream_t stream) {
    const float* x     = (const float*)d_in[0];
    const int*   eidx  = (const int*)d_in[1];
    const int*   etype = (const int*)d_in[2];
    const float* bases0 = (const float*)d_in[3];
    const float* comp0  = (const float*)d_in[4];
    const float* root0  = (const float*)d_in[5];
    const float* bias0  = (const float*)d_in[6];
    const float* bases1 = (const float*)d_in[7];
    const float* comp1  = (const float*)d_in[8];
    const float* root1  = (const float*)d_in[9];
    const float* bias1  = (const float*)d_in[10];
    const float* bases2 = (const float*)d_in[11];
    const float* comp2  = (const float*)d_in[12];
    const float* root2  = (const float*)d_in[13];
    const float* bias2  = (const float*)d_in[14];
    const int* srcp = eidx;
    const int* dstp = eidx + EE;

    char* p = (char*)d_ws;
    auto carve = [&](size_t bytes) -> char* {
        char* r = p;
        p += (bytes + 255) & ~(size_t)255;
        return r;
    };
    int*  cnt    = (int*)carve((size_t)NN * RR * sizeof(int));   // 10 MB
    int*  dcount = (int*)carve((size_t)NN * sizeof(int));
    int*  doff   = (int*)carve((size_t)NN * sizeof(int));
    int*  cursor = (int*)carve((size_t)NN * sizeof(int));
    int*  bsum   = (int*)carve(256 * sizeof(int));
    int4* epack  = (int4*)carve((size_t)EE * sizeof(int4));      // 16 MB
    __hip_bfloat16* h0 = (__hip_bfloat16*)carve((size_t)NN * DIN * 2);
    __hip_bfloat16* h1 = (__hip_bfloat16*)carve((size_t)NN * DIN * 2);
    __hip_bfloat16* h2 = (__hip_bfloat16*)carve((size_t)NN * DIN * 2);
    float* pre = (float*)carve((size_t)NN * 8 * sizeof(float));

    hipMemsetAsync(cnt, 0, (size_t)NN * RR * sizeof(int), stream);
    hipMemsetAsync(dcount, 0, (size_t)NN * sizeof(int), stream);
    hipMemsetAsync(cursor, 0, (size_t)NN * sizeof(int), stream);

    const int EB = (EE + 255) / 256;   // 3907
    const int NB = (NN + 255) / 256;   // 196
    k_hist<<<EB, 256, 0, stream>>>(dstp, etype, cnt, dcount);
    k_scan1<<<NB, 256, 0, stream>>>(dcount, doff, bsum);
    k_scan2<<<1, 256, 0, stream>>>(bsum, NB);
    k_scan3<<<NB, 256, 0, stream>>>(doff, bsum);
    k_scatter<<<EB, 256, 0, stream>>>(srcp, dstp, etype, cnt, doff, cursor, epack);
    k_cast_x<<<(NN * DIN + 255) / 256, 256, 0, stream>>>(x, h0);

    const int NF = (NN + NBW - 1) / NBW;   // 6250
    k_fused<64, true><<<NF, 256, 0, stream>>>(h0, epack, doff, dcount, comp0, bases0, root0, bias0, (void*)h1);
    k_fused<64, true><<<NF, 256, 0, stream>>>(h1, epack, doff, dcount, comp1, bases1, root1, bias1, (void*)h2);
    k_fused<8, false><<<NF, 256, 0, stream>>>(h2, epack, doff, dcount, comp2, bases2, root2, bias2, (void*)pre);
    k_lsm<<<NB, 256, 0, stream>>>(pre, (float*)d_out);
}

// Round 2
// 1015.031 us; speedup vs baseline: 4.1204x; 4.1204x over previous
//
#include <hip/hip_runtime.h>
#include <hip/hip_bf16.h>
#include <stdint.h>

// Problem constants (fixed by the reference)
#define NN   50000
#define RR   50
#define BB   30
#define DIN  64
#define EE   1000000
#define KTOT (BB*DIN + DIN)   // 1984 = 62*32
#define NBW  16               // nodes per workgroup (16-row MFMA tile)
#define ROWE (KTOT + 8)       // padded LDS row: 1992 elems (3984 B)

typedef __attribute__((ext_vector_type(8))) short short8;
typedef __attribute__((ext_vector_type(4))) float floatx4;

#define RFL(x) __builtin_amdgcn_readfirstlane(x)

// ---------------- preprocessing: counting sort of edges by dst ----------------

__global__ void k_hist(const int* __restrict__ dst, const int* __restrict__ et,
                       int* __restrict__ cnt, int* __restrict__ dcount) {
    int e = blockIdx.x * 256 + threadIdx.x;
    if (e < EE) {
        int d = dst[e], r = et[e];
        atomicAdd(&cnt[d * RR + r], 1);
        atomicAdd(&dcount[d], 1);
    }
}

__global__ void k_scan1(const int* __restrict__ dcount, int* __restrict__ doff,
                        int* __restrict__ bsum) {
    __shared__ int sh[256];
    int t = threadIdx.x;
    int i = blockIdx.x * 256 + t;
    int v = (i < NN) ? dcount[i] : 0;
    sh[t] = v;
    __syncthreads();
    for (int s = 1; s < 256; s <<= 1) {
        int add = (t >= s) ? sh[t - s] : 0;
        __syncthreads();
        sh[t] += add;
        __syncthreads();
    }
    int incl = sh[t];
    if (i < NN) doff[i] = incl - v;
    if (t == 255) bsum[blockIdx.x] = incl;
}

__global__ void k_scan2(int* __restrict__ bsum, int nbv) {
    __shared__ int sh[256];
    int t = threadIdx.x;
    int v = (t < nbv) ? bsum[t] : 0;
    sh[t] = v;
    __syncthreads();
    for (int s = 1; s < 256; s <<= 1) {
        int add = (t >= s) ? sh[t - s] : 0;
        __syncthreads();
        sh[t] += add;
        __syncthreads();
    }
    if (t < nbv) bsum[t] = sh[t] - v;
}

__global__ void k_scan3(int* __restrict__ doff, const int* __restrict__ bsum) {
    int i = blockIdx.x * 256 + threadIdx.x;
    if (i < NN) doff[i] += bsum[blockIdx.x];
}

__global__ void k_scatter(const int* __restrict__ src, const int* __restrict__ dst,
                          const int* __restrict__ et, const int* __restrict__ cnt,
                          const int* __restrict__ doff, int* __restrict__ cursor,
                          int4* __restrict__ epack) {
    int e = blockIdx.x * 256 + threadIdx.x;
    if (e < EE) {
        int d = dst[e], r = et[e], s = src[e];
        int p = doff[d] + atomicAdd(&cursor[d], 1);
        float a = 1.0f / (float)cnt[d * RR + r];
        epack[p] = make_int4(s, r, __float_as_int(a), 0);
    }
}

__global__ void k_cast_x(const float* __restrict__ x, __hip_bfloat16* __restrict__ h) {
    int i = blockIdx.x * 256 + threadIdx.x;
    if (i < NN * DIN) h[i] = __float2bfloat16(x[i]);
}

// Build transposed bf16 weights Wt[o][k] for one layer; rows o>=dout zero-padded.
__global__ void k_prep_w(const float* __restrict__ bases, const float* __restrict__ root,
                         short* __restrict__ wt, int dout, int dpad) {
    int idx = blockIdx.x * 256 + threadIdx.x;
    if (idx >= dpad * KTOT) return;
    int o = idx / KTOT, k = idx - o * KTOT;
    float v = 0.f;
    if (o < dout)
        v = (k < BB * DIN) ? bases[k * dout + o] : root[(k - BB * DIN) * dout + o];
    __hip_bfloat16 hb = __float2bfloat16(v);
    wt[o * KTOT + k] = *reinterpret_cast<const short*>(&hb);
}

// ---------------- fused per-layer kernel ----------------
// Phase 1 (VALU, scalarized edge stream): wave wv handles nodes j=wv*4..wv*4+3.
//   Edge records via uniform s_load; comp row via SGPR burst loads; x gather per lane.
//   Result t[j][k] (k<1984: basis-projected aggregation; k in [1920,1984): self x)
//   written to LDS as bf16.
// Phase 2 (MFMA): wave wv computes 16x16 tile of out = t (16xK) * Wt^T (Kx16).
template <int DOUT, bool RELU>
__global__ __launch_bounds__(256, 2)
void k_fused(const __hip_bfloat16* __restrict__ xin,
             const int4* __restrict__ epack,
             const int* __restrict__ doff, const int* __restrict__ dcount,
             const float* __restrict__ comp,     // [R, B] fp32
             const short* __restrict__ Wt,       // [DPAD][KTOT] bf16 (transposed)
             const float* __restrict__ bias,     // [DOUT]
             void* __restrict__ outp) {
    __shared__ __align__(16) __hip_bfloat16 t_tile[NBW][ROWE];   // 63744 B
    const int tid  = threadIdx.x;
    const int lane = tid & 63;
    const int wv   = RFL(tid >> 6);
    const int node0 = blockIdx.x * NBW;

    // ---- phase 1 ----
    for (int jj = 0; jj < 4; ++jj) {
        const int j = wv * 4 + jj;
        const int n = node0 + j;
        float acc[BB + 1];
#pragma unroll
        for (int b = 0; b <= BB; ++b) acc[b] = 0.f;
        if (n < NN) {
            const int beg = RFL(doff[n]);
            const int cnt = RFL(dcount[n]);
            int e = 0;
            for (; e + 2 <= cnt; e += 2) {
                int4 epA = epack[beg + e];
                int4 epB = epack[beg + e + 1];
                const int   sA = RFL(epA.x), rA = RFL(epA.y);
                const float aA = __int_as_float(RFL(epA.z));
                const int   sB = RFL(epB.x), rB = RFL(epB.y);
                const float aB = __int_as_float(RFL(epB.z));
                // issue both gathers before the FMA block
                const float xA = __bfloat162float(xin[sA * DIN + lane]) * aA;
                const float xB = __bfloat162float(xin[sB * DIN + lane]) * aB;
                const float* cA = comp + rA * BB;
                const float* cB = comp + rB * BB;
#pragma unroll
                for (int b = 0; b < BB; ++b) {
                    acc[b] = fmaf(cA[b], xA, acc[b]);
                    acc[b] = fmaf(cB[b], xB, acc[b]);
                }
            }
            if (e < cnt) {
                int4 ep = epack[beg + e];
                const int   s = RFL(ep.x), r = RFL(ep.y);
                const float a = __int_as_float(RFL(ep.z));
                const float xv = __bfloat162float(xin[s * DIN + lane]) * a;
                const float* c = comp + r * BB;
#pragma unroll
                for (int b = 0; b < BB; ++b) acc[b] = fmaf(c[b], xv, acc[b]);
            }
            acc[BB] = __bfloat162float(xin[n * DIN + lane]);   // root/self term
        }
#pragma unroll
        for (int b = 0; b <= BB; ++b)
            t_tile[j][b * DIN + lane] = __float2bfloat16(acc[b]);
    }
    __syncthreads();

    // ---- phase 2: MFMA 16x16x32 bf16, K = 1984 ----
    const int m = lane & 15;         // A row / B col (output col)
    const int q = lane >> 4;         // k-quad
    constexpr int NKC = KTOT / 32;   // 62
    const int col_base = (DOUT == 64) ? wv * 16 : 0;

    const __hip_bfloat16* arow = &t_tile[m][q * 8];
    const short* brow = Wt + (size_t)(col_base + m) * KTOT + q * 8;

    floatx4 acc0 = {0.f, 0.f, 0.f, 0.f};
    floatx4 acc1 = {0.f, 0.f, 0.f, 0.f};
#pragma unroll 4
    for (int kk = 0; kk < NKC; kk += 2) {
        short8 a0 = *reinterpret_cast<const short8*>(arow + kk * 32);
        short8 b0 = *reinterpret_cast<const short8*>(brow + kk * 32);
        short8 a1 = *reinterpret_cast<const short8*>(arow + (kk + 1) * 32);
        short8 b1 = *reinterpret_cast<const short8*>(brow + (kk + 1) * 32);
        acc0 = __builtin_amdgcn_mfma_f32_16x16x32_bf16(a0, b0, acc0, 0, 0, 0);
        acc1 = __builtin_amdgcn_mfma_f32_16x16x32_bf16(a1, b1, acc1, 0, 0, 0);
    }

    // epilogue: C/D layout col=lane&15, row=q*4+reg
    if (DOUT == 64 || (wv == 0 && m < DOUT)) {
        const int o = col_base + m;
        const float bi = bias[o];
#pragma unroll
        for (int r = 0; r < 4; ++r) {
            const int n = node0 + q * 4 + r;
            if (n < NN) {
                float v = acc0[r] + acc1[r] + bi;
                if (RELU) {
                    v = fmaxf(v, 0.f);
                    reinterpret_cast<__hip_bfloat16*>(outp)[(size_t)n * DOUT + o] =
                        __float2bfloat16(v);
                } else {
                    reinterpret_cast<float*>(outp)[(size_t)n * DOUT + o] = v;
                }
            }
        }
    }
}

// ---------------- log_softmax over C=8 ----------------
__global__ void k_lsm(const float* __restrict__ pre, float* __restrict__ out) {
    int n = blockIdx.x * 256 + threadIdx.x;
    if (n < NN) {
        float v[8];
        float mx = -1e30f;
#pragma unroll
        for (int c = 0; c < 8; ++c) { v[c] = pre[n * 8 + c]; mx = fmaxf(mx, v[c]); }
        float s = 0.f;
#pragma unroll
        for (int c = 0; c < 8; ++c) s += expf(v[c] - mx);
        float ls = logf(s);
#pragma unroll
        for (int c = 0; c < 8; ++c) out[n * 8 + c] = v[c] - mx - ls;
    }
}

// ---------------- launch ----------------
extern "C" void kernel_launch(void* const* d_in, const int* in_sizes, int n_in,
                              void* d_out, int out_size, void* d_ws, size_t ws_size,
                              hipStream_t stream) {
    const float* x     = (const float*)d_in[0];
    const int*   eidx  = (const int*)d_in[1];
    const int*   etype = (const int*)d_in[2];
    const float* bases0 = (const float*)d_in[3];
    const float* comp0  = (const float*)d_in[4];
    const float* root0  = (const float*)d_in[5];
    const float* bias0  = (const float*)d_in[6];
    const float* bases1 = (const float*)d_in[7];
    const float* comp1  = (const float*)d_in[8];
    const float* root1  = (const float*)d_in[9];
    const float* bias1  = (const float*)d_in[10];
    const float* bases2 = (const float*)d_in[11];
    const float* comp2  = (const float*)d_in[12];
    const float* root2  = (const float*)d_in[13];
    const float* bias2  = (const float*)d_in[14];
    const int* srcp = eidx;
    const int* dstp = eidx + EE;

    char* p = (char*)d_ws;
    auto carve = [&](size_t bytes) -> char* {
        char* r = p;
        p += (bytes + 255) & ~(size_t)255;
        return r;
    };
    int*  cnt    = (int*)carve((size_t)NN * RR * sizeof(int));   // 10 MB
    int*  dcount = (int*)carve((size_t)NN * sizeof(int));
    int*  doff   = (int*)carve((size_t)NN * sizeof(int));
    int*  cursor = (int*)carve((size_t)NN * sizeof(int));
    int*  bsum   = (int*)carve(256 * sizeof(int));
    int4* epack  = (int4*)carve((size_t)EE * sizeof(int4));      // 16 MB
    __hip_bfloat16* h0 = (__hip_bfloat16*)carve((size_t)NN * DIN * 2);
    __hip_bfloat16* h1 = (__hip_bfloat16*)carve((size_t)NN * DIN * 2);
    __hip_bfloat16* h2 = (__hip_bfloat16*)carve((size_t)NN * DIN * 2);
    float* pre = (float*)carve((size_t)NN * 8 * sizeof(float));
    short* wt0 = (short*)carve((size_t)64 * KTOT * sizeof(short));
    short* wt1 = (short*)carve((size_t)64 * KTOT * sizeof(short));
    short* wt2 = (short*)carve((size_t)16 * KTOT * sizeof(short));

    hipMemsetAsync(cnt, 0, (size_t)NN * RR * sizeof(int), stream);
    hipMemsetAsync(dcount, 0, (size_t)NN * sizeof(int), stream);
    hipMemsetAsync(cursor, 0, (size_t)NN * sizeof(int), stream);

    const int EB = (EE + 255) / 256;   // 3907
    const int NB = (NN + 255) / 256;   // 196
    k_hist<<<EB, 256, 0, stream>>>(dstp, etype, cnt, dcount);
    k_scan1<<<NB, 256, 0, stream>>>(dcount, doff, bsum);
    k_scan2<<<1, 256, 0, stream>>>(bsum, NB);
    k_scan3<<<NB, 256, 0, stream>>>(doff, bsum);
    k_scatter<<<EB, 256, 0, stream>>>(srcp, dstp, etype, cnt, doff, cursor, epack);
    k_cast_x<<<(NN * DIN + 255) / 256, 256, 0, stream>>>(x, h0);
    k_prep_w<<<(64 * KTOT + 255) / 256, 256, 0, stream>>>(bases0, root0, wt0, 64, 64);
    k_prep_w<<<(64 * KTOT + 255) / 256, 256, 0, stream>>>(bases1, root1, wt1, 64, 64);
    k_prep_w<<<(16 * KTOT + 255) / 256, 256, 0, stream>>>(bases2, root2, wt2, 8, 16);

    const int NF = (NN + NBW - 1) / NBW;   // 3125
    k_fused<64, true ><<<NF, 256, 0, stream>>>(h0, epack, doff, dcount, comp0, wt0, bias0, (void*)h1);
    k_fused<64, true ><<<NF, 256, 0, stream>>>(h1, epack, doff, dcount, comp1, wt1, bias1, (void*)h2);
    k_fused<8,  false><<<NF, 256, 0, stream>>>(h2, epack, doff, dcount, comp2, wt2, bias2, (void*)pre);
    k_lsm<<<NB, 256, 0, stream>>>(pre, (float*)d_out);
}

// Round 3
// 916.415 us; speedup vs baseline: 4.5638x; 1.1076x over previous
//
#include <hip/hip_runtime.h>
#include <hip/hip_bf16.h>
#include <stdint.h>

// Problem constants (fixed by the reference)
#define NN   50000
#define RR   50
#define BB   30
#define DIN  64
#define EE   1000000
#define KTOT (BB*DIN + DIN)   // 1984 = 62*32
#define NBW  16               // nodes per workgroup (16-row MFMA tile)
#define ROWE (KTOT + 8)       // padded LDS row: 1992 elems (3984 B)
#define CPAD 32               // comp row padded 30 -> 32 floats

typedef __attribute__((ext_vector_type(8))) short short8;
typedef __attribute__((ext_vector_type(4))) float floatx4;

#define RFL(x) __builtin_amdgcn_readfirstlane(x)

// ---------------- preprocessing: counting sort of edges by dst ----------------

__global__ void k_hist(const int* __restrict__ dst, const int* __restrict__ et,
                       int* __restrict__ cnt, int* __restrict__ dcount) {
    int e = blockIdx.x * 256 + threadIdx.x;
    if (e < EE) {
        int d = dst[e], r = et[e];
        atomicAdd(&cnt[d * RR + r], 1);
        atomicAdd(&dcount[d], 1);
    }
}

__global__ void k_scan1(const int* __restrict__ dcount, int* __restrict__ doff,
                        int* __restrict__ bsum) {
    __shared__ int sh[256];
    int t = threadIdx.x;
    int i = blockIdx.x * 256 + t;
    int v = (i < NN) ? dcount[i] : 0;
    sh[t] = v;
    __syncthreads();
    for (int s = 1; s < 256; s <<= 1) {
        int add = (t >= s) ? sh[t - s] : 0;
        __syncthreads();
        sh[t] += add;
        __syncthreads();
    }
    int incl = sh[t];
    if (i < NN) doff[i] = incl - v;
    if (t == 255) bsum[blockIdx.x] = incl;
}

__global__ void k_scan2(int* __restrict__ bsum, int nbv) {
    __shared__ int sh[256];
    int t = threadIdx.x;
    int v = (t < nbv) ? bsum[t] : 0;
    sh[t] = v;
    __syncthreads();
    for (int s = 1; s < 256; s <<= 1) {
        int add = (t >= s) ? sh[t - s] : 0;
        __syncthreads();
        sh[t] += add;
        __syncthreads();
    }
    if (t < nbv) bsum[t] = sh[t] - v;
}

__global__ void k_scan3(int* __restrict__ doff, const int* __restrict__ bsum) {
    int i = blockIdx.x * 256 + threadIdx.x;
    if (i < NN) doff[i] += bsum[blockIdx.x];
}

__global__ void k_scatter(const int* __restrict__ src, const int* __restrict__ dst,
                          const int* __restrict__ et, const int* __restrict__ cnt,
                          const int* __restrict__ doff, int* __restrict__ cursor,
                          int4* __restrict__ epack) {
    int e = blockIdx.x * 256 + threadIdx.x;
    if (e < EE) {
        int d = dst[e], r = et[e], s = src[e];
        int p = doff[d] + atomicAdd(&cursor[d], 1);
        float a = 1.0f / (float)cnt[d * RR + r];
        epack[p] = make_int4(s, r, __float_as_int(a), 0);
    }
}

__global__ void k_cast_x(const float* __restrict__ x, __hip_bfloat16* __restrict__ h) {
    int i = blockIdx.x * 256 + threadIdx.x;
    if (i < NN * DIN) h[i] = __float2bfloat16(x[i]);
}

// comp [R,30] fp32 -> padded [R,32] fp32 (zeros in slots 30,31), 16B-aligned rows
__global__ void k_prep_comp(const float* __restrict__ comp, float* __restrict__ compP) {
    int idx = blockIdx.x * 256 + threadIdx.x;
    if (idx < RR * CPAD) {
        int r = idx / CPAD, i = idx - r * CPAD;
        compP[idx] = (i < BB) ? comp[r * BB + i] : 0.f;
    }
}

// Build transposed bf16 weights Wt[o][k] for one layer; rows o>=dout zero-padded.
__global__ void k_prep_w(const float* __restrict__ bases, const float* __restrict__ root,
                         short* __restrict__ wt, int dout, int dpad) {
    int idx = blockIdx.x * 256 + threadIdx.x;
    if (idx >= dpad * KTOT) return;
    int o = idx / KTOT, k = idx - o * KTOT;
    float v = 0.f;
    if (o < dout)
        v = (k < BB * DIN) ? bases[k * dout + o] : root[(k - BB * DIN) * dout + o];
    __hip_bfloat16 hb = __float2bfloat16(v);
    wt[o * KTOT + k] = *reinterpret_cast<const short*>(&hb);
}

// ---------------- fused per-layer kernel ----------------
// Phase 1: wave wv handles nodes j=wv*4..wv*4+3. Unroll-4 edge pipeline:
//   4 records (scalar loads) + 4 x-gathers in flight, then 4 x 8 float4 FMAs
//   (v_pk_fma_f32) against padded comp rows. acc in 8 float4 regs.
// Phase 2 (MFMA): wave wv computes 16x16 tile of out = t (16xK) * Wt^T (Kx16).
template <int DOUT, bool RELU>
__global__ __launch_bounds__(256, 2)
void k_fused(const __hip_bfloat16* __restrict__ xin,
             const int4* __restrict__ epack,
             const int* __restrict__ doff, const int* __restrict__ dcount,
             const float* __restrict__ compP,    // [R, 32] fp32 padded
             const short* __restrict__ Wt,       // [DPAD][KTOT] bf16 (transposed)
             const float* __restrict__ bias,     // [DOUT]
             void* __restrict__ outp) {
    __shared__ __align__(16) __hip_bfloat16 t_tile[NBW][ROWE];   // 63744 B
    const int tid  = threadIdx.x;
    const int lane = tid & 63;
    const int wv   = RFL(tid >> 6);
    const int node0 = blockIdx.x * NBW;

    // ---- phase 1 ----
    for (int jj = 0; jj < 4; ++jj) {
        const int j = wv * 4 + jj;
        const int n = node0 + j;
        floatx4 acc4[8];
#pragma unroll
        for (int u = 0; u < 8; ++u) acc4[u] = (floatx4){0.f, 0.f, 0.f, 0.f};
        float xself = 0.f;
        if (n < NN) {
            const int beg = RFL(doff[n]);
            const int cnt = RFL(dcount[n]);
            int e = 0;
            for (; e + 4 <= cnt; e += 4) {
                // 4 uniform record loads (consecutive 16B each)
                int4 ep0 = epack[beg + e + 0];
                int4 ep1 = epack[beg + e + 1];
                int4 ep2 = epack[beg + e + 2];
                int4 ep3 = epack[beg + e + 3];
                const int s0 = RFL(ep0.x), r0 = RFL(ep0.y);
                const int s1 = RFL(ep1.x), r1 = RFL(ep1.y);
                const int s2 = RFL(ep2.x), r2 = RFL(ep2.y);
                const int s3 = RFL(ep3.x), r3 = RFL(ep3.y);
                const float a0 = __int_as_float(RFL(ep0.z));
                const float a1 = __int_as_float(RFL(ep1.z));
                const float a2 = __int_as_float(RFL(ep2.z));
                const float a3 = __int_as_float(RFL(ep3.z));
                // issue all 4 gathers before FMA blocks
                const float x0 = __bfloat162float(xin[s0 * DIN + lane]) * a0;
                const float x1 = __bfloat162float(xin[s1 * DIN + lane]) * a1;
                const float x2 = __bfloat162float(xin[s2 * DIN + lane]) * a2;
                const float x3 = __bfloat162float(xin[s3 * DIN + lane]) * a3;
                const floatx4* c0 = (const floatx4*)(compP + r0 * CPAD);
                const floatx4* c1 = (const floatx4*)(compP + r1 * CPAD);
                const floatx4* c2 = (const floatx4*)(compP + r2 * CPAD);
                const floatx4* c3 = (const floatx4*)(compP + r3 * CPAD);
                const floatx4 xb0 = {x0, x0, x0, x0};
                const floatx4 xb1 = {x1, x1, x1, x1};
                const floatx4 xb2 = {x2, x2, x2, x2};
                const floatx4 xb3 = {x3, x3, x3, x3};
#pragma unroll
                for (int u = 0; u < 8; ++u) acc4[u] = c0[u] * xb0 + acc4[u];
#pragma unroll
                for (int u = 0; u < 8; ++u) acc4[u] = c1[u] * xb1 + acc4[u];
#pragma unroll
                for (int u = 0; u < 8; ++u) acc4[u] = c2[u] * xb2 + acc4[u];
#pragma unroll
                for (int u = 0; u < 8; ++u) acc4[u] = c3[u] * xb3 + acc4[u];
            }
            for (; e < cnt; ++e) {
                int4 ep = epack[beg + e];
                const int   s = RFL(ep.x), r = RFL(ep.y);
                const float a = __int_as_float(RFL(ep.z));
                const float xv = __bfloat162float(xin[s * DIN + lane]) * a;
                const floatx4* c = (const floatx4*)(compP + r * CPAD);
                const floatx4 xb = {xv, xv, xv, xv};
#pragma unroll
                for (int u = 0; u < 8; ++u) acc4[u] = c[u] * xb + acc4[u];
            }
            xself = __bfloat162float(xin[n * DIN + lane]);   // root/self term
        }
#pragma unroll
        for (int b = 0; b < BB; ++b)
            t_tile[j][b * DIN + lane] = __float2bfloat16(acc4[b >> 2][b & 3]);
        t_tile[j][BB * DIN + lane] = __float2bfloat16(xself);
    }
    __syncthreads();

    // ---- phase 2: MFMA 16x16x32 bf16, K = 1984 ----
    const int m = lane & 15;         // A row / B col (output col)
    const int q = lane >> 4;         // k-quad
    constexpr int NKC = KTOT / 32;   // 62
    const int col_base = (DOUT == 64) ? wv * 16 : 0;

    const __hip_bfloat16* arow = &t_tile[m][q * 8];
    const short* brow = Wt + (size_t)(col_base + m) * KTOT + q * 8;

    floatx4 acc0 = {0.f, 0.f, 0.f, 0.f};
    floatx4 acc1 = {0.f, 0.f, 0.f, 0.f};
#pragma unroll 4
    for (int kk = 0; kk < NKC; kk += 2) {
        short8 a0 = *reinterpret_cast<const short8*>(arow + kk * 32);
        short8 b0 = *reinterpret_cast<const short8*>(brow + kk * 32);
        short8 a1 = *reinterpret_cast<const short8*>(arow + (kk + 1) * 32);
        short8 b1 = *reinterpret_cast<const short8*>(brow + (kk + 1) * 32);
        acc0 = __builtin_amdgcn_mfma_f32_16x16x32_bf16(a0, b0, acc0, 0, 0, 0);
        acc1 = __builtin_amdgcn_mfma_f32_16x16x32_bf16(a1, b1, acc1, 0, 0, 0);
    }

    // epilogue: C/D layout col=lane&15, row=q*4+reg
    if (DOUT == 64 || (wv == 0 && m < DOUT)) {
        const int o = col_base + m;
        const float bi = bias[o];
#pragma unroll
        for (int r = 0; r < 4; ++r) {
            const int n = node0 + q * 4 + r;
            if (n < NN) {
                float v = acc0[r] + acc1[r] + bi;
                if (RELU) {
                    v = fmaxf(v, 0.f);
                    reinterpret_cast<__hip_bfloat16*>(outp)[(size_t)n * DOUT + o] =
                        __float2bfloat16(v);
                } else {
                    reinterpret_cast<float*>(outp)[(size_t)n * DOUT + o] = v;
                }
            }
        }
    }
}

// ---------------- log_softmax over C=8 ----------------
__global__ void k_lsm(const float* __restrict__ pre, float* __restrict__ out) {
    int n = blockIdx.x * 256 + threadIdx.x;
    if (n < NN) {
        float v[8];
        float mx = -1e30f;
#pragma unroll
        for (int c = 0; c < 8; ++c) { v[c] = pre[n * 8 + c]; mx = fmaxf(mx, v[c]); }
        float s = 0.f;
#pragma unroll
        for (int c = 0; c < 8; ++c) s += expf(v[c] - mx);
        float ls = logf(s);
#pragma unroll
        for (int c = 0; c < 8; ++c) out[n * 8 + c] = v[c] - mx - ls;
    }
}

// ---------------- launch ----------------
extern "C" void kernel_launch(void* const* d_in, const int* in_sizes, int n_in,
                              void* d_out, int out_size, void* d_ws, size_t ws_size,
                              hipStream_t stream) {
    const float* x     = (const float*)d_in[0];
    const int*   eidx  = (const int*)d_in[1];
    const int*   etype = (const int*)d_in[2];
    const float* bases0 = (const float*)d_in[3];
    const float* comp0  = (const float*)d_in[4];
    const float* root0  = (const float*)d_in[5];
    const float* bias0  = (const float*)d_in[6];
    const float* bases1 = (const float*)d_in[7];
    const float* comp1  = (const float*)d_in[8];
    const float* root1  = (const float*)d_in[9];
    const float* bias1  = (const float*)d_in[10];
    const float* bases2 = (const float*)d_in[11];
    const float* comp2  = (const float*)d_in[12];
    const float* root2  = (const float*)d_in[13];
    const float* bias2  = (const float*)d_in[14];
    const int* srcp = eidx;
    const int* dstp = eidx + EE;

    char* p = (char*)d_ws;
    auto carve = [&](size_t bytes) -> char* {
        char* r = p;
        p += (bytes + 255) & ~(size_t)255;
        return r;
    };
    int*  cnt    = (int*)carve((size_t)NN * RR * sizeof(int));   // 10 MB
    int*  dcount = (int*)carve((size_t)NN * sizeof(int));
    int*  doff   = (int*)carve((size_t)NN * sizeof(int));
    int*  cursor = (int*)carve((size_t)NN * sizeof(int));
    int*  bsum   = (int*)carve(256 * sizeof(int));
    int4* epack  = (int4*)carve((size_t)EE * sizeof(int4));      // 16 MB
    __hip_bfloat16* h0 = (__hip_bfloat16*)carve((size_t)NN * DIN * 2);
    __hip_bfloat16* h1 = (__hip_bfloat16*)carve((size_t)NN * DIN * 2);
    __hip_bfloat16* h2 = (__hip_bfloat16*)carve((size_t)NN * DIN * 2);
    float* pre = (float*)carve((size_t)NN * 8 * sizeof(float));
    short* wt0 = (short*)carve((size_t)64 * KTOT * sizeof(short));
    short* wt1 = (short*)carve((size_t)64 * KTOT * sizeof(short));
    short* wt2 = (short*)carve((size_t)16 * KTOT * sizeof(short));
    float* cp0 = (float*)carve((size_t)RR * CPAD * sizeof(float));
    float* cp1 = (float*)carve((size_t)RR * CPAD * sizeof(float));
    float* cp2 = (float*)carve((size_t)RR * CPAD * sizeof(float));

    hipMemsetAsync(cnt, 0, (size_t)NN * RR * sizeof(int), stream);
    hipMemsetAsync(dcount, 0, (size_t)NN * sizeof(int), stream);
    hipMemsetAsync(cursor, 0, (size_t)NN * sizeof(int), stream);

    const int EB = (EE + 255) / 256;   // 3907
    const int NB = (NN + 255) / 256;   // 196
    k_hist<<<EB, 256, 0, stream>>>(dstp, etype, cnt, dcount);
    k_scan1<<<NB, 256, 0, stream>>>(dcount, doff, bsum);
    k_scan2<<<1, 256, 0, stream>>>(bsum, NB);
    k_scan3<<<NB, 256, 0, stream>>>(doff, bsum);
    k_scatter<<<EB, 256, 0, stream>>>(srcp, dstp, etype, cnt, doff, cursor, epack);
    k_cast_x<<<(NN * DIN + 255) / 256, 256, 0, stream>>>(x, h0);
    k_prep_comp<<<(RR * CPAD + 255) / 256, 256, 0, stream>>>(comp0, cp0);
    k_prep_comp<<<(RR * CPAD + 255) / 256, 256, 0, stream>>>(comp1, cp1);
    k_prep_comp<<<(RR * CPAD + 255) / 256, 256, 0, stream>>>(comp2, cp2);
    k_prep_w<<<(64 * KTOT + 255) / 256, 256, 0, stream>>>(bases0, root0, wt0, 64, 64);
    k_prep_w<<<(64 * KTOT + 255) / 256, 256, 0, stream>>>(bases1, root1, wt1, 64, 64);
    k_prep_w<<<(16 * KTOT + 255) / 256, 256, 0, stream>>>(bases2, root2, wt2, 8, 16);

    const int NF = (NN + NBW - 1) / NBW;   // 3125
    k_fused<64, true ><<<NF, 256, 0, stream>>>(h0, epack, doff, dcount, cp0, wt0, bias0, (void*)h1);
    k_fused<64, true ><<<NF, 256, 0, stream>>>(h1, epack, doff, dcount, cp1, wt1, bias1, (void*)h2);
    k_fused<8,  false><<<NF, 256, 0, stream>>>(h2, epack, doff, dcount, cp2, wt2, bias2, (void*)pre);
    k_lsm<<<NB, 256, 0, stream>>>(pre, (float*)d_out);
}

// Round 4
// 689.140 us; speedup vs baseline: 6.0689x; 1.3298x over previous
//
#include <hip/hip_runtime.h>
#include <hip/hip_bf16.h>
#include <stdint.h>

// Problem constants (fixed by the reference)
#define NN   50000
#define RR   50
#define BB   30
#define DIN  64
#define EE   1000000
#define KTOT (BB*DIN + DIN)   // 1984 = 62*32
#define NBW  16               // nodes per workgroup (16-row MFMA tile)
#define ROWE (KTOT + 8)       // padded LDS row: 1992 elems (3984 B)
#define CPAD 32               // comp row padded 30 -> 32 floats

typedef __attribute__((ext_vector_type(8))) short short8;
typedef __attribute__((ext_vector_type(4))) float floatx4;

#define RFL(x) __builtin_amdgcn_readfirstlane(x)

// ---------------- preprocessing: counting sort of edges by dst ----------------

__global__ void k_hist(const int* __restrict__ dst, const int* __restrict__ et,
                       int* __restrict__ cnt, int* __restrict__ dcount) {
    int e = blockIdx.x * 256 + threadIdx.x;
    if (e < EE) {
        int d = dst[e], r = et[e];
        atomicAdd(&cnt[d * RR + r], 1);
        atomicAdd(&dcount[d], 1);
    }
}

__global__ void k_scan1(const int* __restrict__ dcount, int* __restrict__ doff,
                        int* __restrict__ bsum) {
    __shared__ int sh[256];
    int t = threadIdx.x;
    int i = blockIdx.x * 256 + t;
    int v = (i < NN) ? dcount[i] : 0;
    sh[t] = v;
    __syncthreads();
    for (int s = 1; s < 256; s <<= 1) {
        int add = (t >= s) ? sh[t - s] : 0;
        __syncthreads();
        sh[t] += add;
        __syncthreads();
    }
    int incl = sh[t];
    if (i < NN) doff[i] = incl - v;
    if (t == 255) bsum[blockIdx.x] = incl;
}

__global__ void k_scan2(int* __restrict__ bsum, int nbv) {
    __shared__ int sh[256];
    int t = threadIdx.x;
    int v = (t < nbv) ? bsum[t] : 0;
    sh[t] = v;
    __syncthreads();
    for (int s = 1; s < 256; s <<= 1) {
        int add = (t >= s) ? sh[t - s] : 0;
        __syncthreads();
        sh[t] += add;
        __syncthreads();
    }
    if (t < nbv) bsum[t] = sh[t] - v;
}

__global__ void k_scan3(int* __restrict__ doff, const int* __restrict__ bsum) {
    int i = blockIdx.x * 256 + threadIdx.x;
    if (i < NN) doff[i] += bsum[blockIdx.x];
}

__global__ void k_scatter(const int* __restrict__ src, const int* __restrict__ dst,
                          const int* __restrict__ et, const int* __restrict__ cnt,
                          const int* __restrict__ doff, int* __restrict__ cursor,
                          int4* __restrict__ epack) {
    int e = blockIdx.x * 256 + threadIdx.x;
    if (e < EE) {
        int d = dst[e], r = et[e], s = src[e];
        int p = doff[d] + atomicAdd(&cursor[d], 1);
        float a = 1.0f / (float)cnt[d * RR + r];
        epack[p] = make_int4(s, r, __float_as_int(a), 0);
    }
}

__global__ void k_cast_x(const float* __restrict__ x, __hip_bfloat16* __restrict__ h) {
    int i = blockIdx.x * 256 + threadIdx.x;
    if (i < NN * DIN) h[i] = __float2bfloat16(x[i]);
}

// comp [R,30] fp32 -> padded [R,32] fp32 (zeros in slots 30,31), 16B-aligned rows
__global__ void k_prep_comp(const float* __restrict__ comp, float* __restrict__ compP) {
    int idx = blockIdx.x * 256 + threadIdx.x;
    if (idx < RR * CPAD) {
        int r = idx / CPAD, i = idx - r * CPAD;
        compP[idx] = (i < BB) ? comp[r * BB + i] : 0.f;
    }
}

// Build transposed bf16 weights Wt[o][k] for one layer; rows o>=dout zero-padded.
__global__ void k_prep_w(const float* __restrict__ bases, const float* __restrict__ root,
                         short* __restrict__ wt, int dout, int dpad) {
    int idx = blockIdx.x * 256 + threadIdx.x;
    if (idx >= dpad * KTOT) return;
    int o = idx / KTOT, k = idx - o * KTOT;
    float v = 0.f;
    if (o < dout)
        v = (k < BB * DIN) ? bases[k * dout + o] : root[(k - BB * DIN) * dout + o];
    __hip_bfloat16 hb = __float2bfloat16(v);
    wt[o * KTOT + k] = *reinterpret_cast<const short*>(&hb);
}

// ---------------- fused per-layer kernel ----------------
// 512 threads = 8 waves. Phase 1: wave wv owns nodes wv*2, wv*2+1; interleaved
// edge walk (2 chains x unroll 2 = 4 gathers in flight). Phase 2: 8 waves split
// the K=62-step MFMA loop (DOUT=64: 4 col tiles x 2 k-halves; DOUT=8: 8 k-parts),
// partials reduced through LDS.
template <int DOUT, bool RELU>
__global__ __launch_bounds__(512, 4)
void k_fused(const __hip_bfloat16* __restrict__ xin,
             const int4* __restrict__ epack,
             const int* __restrict__ doff, const int* __restrict__ dcount,
             const float* __restrict__ compP,    // [R, 32] fp32 padded
             const short* __restrict__ Wt,       // [DPAD][KTOT] bf16 (transposed)
             const float* __restrict__ bias,     // [DOUT]
             void* __restrict__ outp) {
    __shared__ __align__(16) char smem_raw[NBW * ROWE * 2];   // 63744 B
    auto t_tile = reinterpret_cast<__hip_bfloat16(*)[ROWE]>(smem_raw);
    const int tid  = threadIdx.x;
    const int lane = tid & 63;
    const int wv   = RFL(tid >> 6);          // 0..7
    const int node0 = blockIdx.x * NBW;

    // ---- phase 1: 2 nodes per wave, interleaved ----
    {
        const int jA = wv * 2, jB = jA + 1;
        const int nA = node0 + jA, nB = node0 + jB;
        floatx4 accA[8], accB[8];
#pragma unroll
        for (int u = 0; u < 8; ++u) {
            accA[u] = (floatx4){0.f, 0.f, 0.f, 0.f};
            accB[u] = (floatx4){0.f, 0.f, 0.f, 0.f};
        }
        const int begA = RFL(doff[nA]), cntA = RFL(dcount[nA]);
        const int begB = RFL(doff[nB]), cntB = RFL(dcount[nB]);
        const int mnc = (cntA < cntB ? cntA : cntB) & ~1;

        for (int i = 0; i < mnc; i += 2) {
            int4 a0 = epack[begA + i];
            int4 a1 = epack[begA + i + 1];
            int4 b0 = epack[begB + i];
            int4 b1 = epack[begB + i + 1];
            const int sa0 = RFL(a0.x), ra0 = RFL(a0.y);
            const int sa1 = RFL(a1.x), ra1 = RFL(a1.y);
            const int sb0 = RFL(b0.x), rb0 = RFL(b0.y);
            const int sb1 = RFL(b1.x), rb1 = RFL(b1.y);
            const float aa0 = __int_as_float(RFL(a0.z));
            const float aa1 = __int_as_float(RFL(a1.z));
            const float ab0 = __int_as_float(RFL(b0.z));
            const float ab1 = __int_as_float(RFL(b1.z));
            // issue all 4 gathers up front
            const float xa0 = __bfloat162float(xin[sa0 * DIN + lane]) * aa0;
            const float xa1 = __bfloat162float(xin[sa1 * DIN + lane]) * aa1;
            const float xb0 = __bfloat162float(xin[sb0 * DIN + lane]) * ab0;
            const float xb1 = __bfloat162float(xin[sb1 * DIN + lane]) * ab1;
            const floatx4* ca0 = (const floatx4*)(compP + ra0 * CPAD);
            const floatx4* ca1 = (const floatx4*)(compP + ra1 * CPAD);
            const floatx4* cb0 = (const floatx4*)(compP + rb0 * CPAD);
            const floatx4* cb1 = (const floatx4*)(compP + rb1 * CPAD);
            const floatx4 va0 = {xa0, xa0, xa0, xa0};
            const floatx4 va1 = {xa1, xa1, xa1, xa1};
            const floatx4 vb0 = {xb0, xb0, xb0, xb0};
            const floatx4 vb1 = {xb1, xb1, xb1, xb1};
#pragma unroll
            for (int u = 0; u < 8; ++u) accA[u] = ca0[u] * va0 + accA[u];
#pragma unroll
            for (int u = 0; u < 8; ++u) accB[u] = cb0[u] * vb0 + accB[u];
#pragma unroll
            for (int u = 0; u < 8; ++u) accA[u] = ca1[u] * va1 + accA[u];
#pragma unroll
            for (int u = 0; u < 8; ++u) accB[u] = cb1[u] * vb1 + accB[u];
        }

        // drain A
        int i = mnc;
        for (; i + 2 <= cntA; i += 2) {
            int4 a0 = epack[begA + i];
            int4 a1 = epack[begA + i + 1];
            const int sa0 = RFL(a0.x), ra0 = RFL(a0.y);
            const int sa1 = RFL(a1.x), ra1 = RFL(a1.y);
            const float aa0 = __int_as_float(RFL(a0.z));
            const float aa1 = __int_as_float(RFL(a1.z));
            const float xa0 = __bfloat162float(xin[sa0 * DIN + lane]) * aa0;
            const float xa1 = __bfloat162float(xin[sa1 * DIN + lane]) * aa1;
            const floatx4* ca0 = (const floatx4*)(compP + ra0 * CPAD);
            const floatx4* ca1 = (const floatx4*)(compP + ra1 * CPAD);
            const floatx4 va0 = {xa0, xa0, xa0, xa0};
            const floatx4 va1 = {xa1, xa1, xa1, xa1};
#pragma unroll
            for (int u = 0; u < 8; ++u) accA[u] = ca0[u] * va0 + accA[u];
#pragma unroll
            for (int u = 0; u < 8; ++u) accA[u] = ca1[u] * va1 + accA[u];
        }
        if (i < cntA) {
            int4 a0 = epack[begA + i];
            const int sa0 = RFL(a0.x), ra0 = RFL(a0.y);
            const float aa0 = __int_as_float(RFL(a0.z));
            const float xa0 = __bfloat162float(xin[sa0 * DIN + lane]) * aa0;
            const floatx4* ca0 = (const floatx4*)(compP + ra0 * CPAD);
            const floatx4 va0 = {xa0, xa0, xa0, xa0};
#pragma unroll
            for (int u = 0; u < 8; ++u) accA[u] = ca0[u] * va0 + accA[u];
        }
        // drain B
        i = mnc;
        for (; i + 2 <= cntB; i += 2) {
            int4 b0 = epack[begB + i];
            int4 b1 = epack[begB + i + 1];
            const int sb0 = RFL(b0.x), rb0 = RFL(b0.y);
            const int sb1 = RFL(b1.x), rb1 = RFL(b1.y);
            const float ab0 = __int_as_float(RFL(b0.z));
            const float ab1 = __int_as_float(RFL(b1.z));
            const float xb0 = __bfloat162float(xin[sb0 * DIN + lane]) * ab0;
            const float xb1 = __bfloat162float(xin[sb1 * DIN + lane]) * ab1;
            const floatx4* cb0 = (const floatx4*)(compP + rb0 * CPAD);
            const floatx4* cb1 = (const floatx4*)(compP + rb1 * CPAD);
            const floatx4 vb0 = {xb0, xb0, xb0, xb0};
            const floatx4 vb1 = {xb1, xb1, xb1, xb1};
#pragma unroll
            for (int u = 0; u < 8; ++u) accB[u] = cb0[u] * vb0 + accB[u];
#pragma unroll
            for (int u = 0; u < 8; ++u) accB[u] = cb1[u] * vb1 + accB[u];
        }
        if (i < cntB) {
            int4 b0 = epack[begB + i];
            const int sb0 = RFL(b0.x), rb0 = RFL(b0.y);
            const float ab0 = __int_as_float(RFL(b0.z));
            const float xb0 = __bfloat162float(xin[sb0 * DIN + lane]) * ab0;
            const floatx4* cb0 = (const floatx4*)(compP + rb0 * CPAD);
            const floatx4 vb0 = {xb0, xb0, xb0, xb0};
#pragma unroll
            for (int u = 0; u < 8; ++u) accB[u] = cb0[u] * vb0 + accB[u];
        }

        const float xsA = __bfloat162float(xin[nA * DIN + lane]);
        const float xsB = __bfloat162float(xin[nB * DIN + lane]);
#pragma unroll
        for (int b = 0; b < BB; ++b) {
            t_tile[jA][b * DIN + lane] = __float2bfloat16(accA[b >> 2][b & 3]);
            t_tile[jB][b * DIN + lane] = __float2bfloat16(accB[b >> 2][b & 3]);
        }
        t_tile[jA][BB * DIN + lane] = __float2bfloat16(xsA);
        t_tile[jB][BB * DIN + lane] = __float2bfloat16(xsB);
    }
    __syncthreads();

    // ---- phase 2: MFMA 16x16x32 bf16, K = 1984, split across 8 waves ----
    const int m = lane & 15;
    const int q = lane >> 4;
    int kk0, nsteps, col_base;
    if (DOUT == 64) {
        kk0 = (wv >> 2) * 31; nsteps = 31; col_base = (wv & 3) * 16;
    } else {
        kk0 = wv * 8; nsteps = (wv == 7) ? 6 : 8; col_base = 0;
    }
    const __hip_bfloat16* arow = &t_tile[m][q * 8];
    const short* brow = Wt + (size_t)(col_base + m) * KTOT + q * 8;

    floatx4 acc0 = {0.f, 0.f, 0.f, 0.f};
    floatx4 acc1 = {0.f, 0.f, 0.f, 0.f};
    int s = 0;
    for (; s + 2 <= nsteps; s += 2) {
        const int kk = kk0 + s;
        short8 a0 = *reinterpret_cast<const short8*>(arow + kk * 32);
        short8 b0 = *reinterpret_cast<const short8*>(brow + kk * 32);
        short8 a1 = *reinterpret_cast<const short8*>(arow + (kk + 1) * 32);
        short8 b1 = *reinterpret_cast<const short8*>(brow + (kk + 1) * 32);
        acc0 = __builtin_amdgcn_mfma_f32_16x16x32_bf16(a0, b0, acc0, 0, 0, 0);
        acc1 = __builtin_amdgcn_mfma_f32_16x16x32_bf16(a1, b1, acc1, 0, 0, 0);
    }
    if (s < nsteps) {
        const int kk = kk0 + s;
        short8 a0 = *reinterpret_cast<const short8*>(arow + kk * 32);
        short8 b0 = *reinterpret_cast<const short8*>(brow + kk * 32);
        acc0 = __builtin_amdgcn_mfma_f32_16x16x32_bf16(a0, b0, acc0, 0, 0, 0);
    }
    floatx4 P = acc0 + acc1;

    __syncthreads();                       // all t_tile reads done
    float* red = (float*)smem_raw;         // reuse LDS for partial reduction

    if (DOUT == 64) {
        if (wv >= 4)
            *(floatx4*)(red + ((wv - 4) * 64 + lane) * 4) = P;
        __syncthreads();
        if (wv < 4) {
            P += *(const floatx4*)(red + (wv * 64 + lane) * 4);
            const int o = col_base + m;
            const float bi = bias[o];
#pragma unroll
            for (int r = 0; r < 4; ++r) {
                const int n = node0 + q * 4 + r;
                if (n < NN) {
                    float v = P[r] + bi;
                    if (RELU) {
                        v = fmaxf(v, 0.f);
                        reinterpret_cast<__hip_bfloat16*>(outp)[(size_t)n * DOUT + o] =
                            __float2bfloat16(v);
                    } else {
                        reinterpret_cast<float*>(outp)[(size_t)n * DOUT + o] = v;
                    }
                }
            }
        }
    } else {
        if (wv > 0)
            *(floatx4*)(red + ((wv - 1) * 64 + lane) * 4) = P;
        __syncthreads();
        if (wv == 0) {
#pragma unroll
            for (int w = 0; w < 7; ++w)
                P += *(const floatx4*)(red + (w * 64 + lane) * 4);
            if (m < DOUT) {
                const int o = m;
                const float bi = bias[o];
#pragma unroll
                for (int r = 0; r < 4; ++r) {
                    const int n = node0 + q * 4 + r;
                    if (n < NN) {
                        float v = P[r] + bi;
                        reinterpret_cast<float*>(outp)[(size_t)n * DOUT + o] = v;
                    }
                }
            }
        }
    }
}

// ---------------- log_softmax over C=8 ----------------
__global__ void k_lsm(const float* __restrict__ pre, float* __restrict__ out) {
    int n = blockIdx.x * 256 + threadIdx.x;
    if (n < NN) {
        float v[8];
        float mx = -1e30f;
#pragma unroll
        for (int c = 0; c < 8; ++c) { v[c] = pre[n * 8 + c]; mx = fmaxf(mx, v[c]); }
        float s = 0.f;
#pragma unroll
        for (int c = 0; c < 8; ++c) s += expf(v[c] - mx);
        float ls = logf(s);
#pragma unroll
        for (int c = 0; c < 8; ++c) out[n * 8 + c] = v[c] - mx - ls;
    }
}

// ---------------- launch ----------------
extern "C" void kernel_launch(void* const* d_in, const int* in_sizes, int n_in,
                              void* d_out, int out_size, void* d_ws, size_t ws_size,
                              hipStream_t stream) {
    const float* x     = (const float*)d_in[0];
    const int*   eidx  = (const int*)d_in[1];
    const int*   etype = (const int*)d_in[2];
    const float* bases0 = (const float*)d_in[3];
    const float* comp0  = (const float*)d_in[4];
    const float* root0  = (const float*)d_in[5];
    const float* bias0  = (const float*)d_in[6];
    const float* bases1 = (const float*)d_in[7];
    const float* comp1  = (const float*)d_in[8];
    const float* root1  = (const float*)d_in[9];
    const float* bias1  = (const float*)d_in[10];
    const float* bases2 = (const float*)d_in[11];
    const float* comp2  = (const float*)d_in[12];
    const float* root2  = (const float*)d_in[13];
    const float* bias2  = (const float*)d_in[14];
    const int* srcp = eidx;
    const int* dstp = eidx + EE;

    char* p = (char*)d_ws;
    auto carve = [&](size_t bytes) -> char* {
        char* r = p;
        p += (bytes + 255) & ~(size_t)255;
        return r;
    };
    int*  cnt    = (int*)carve((size_t)NN * RR * sizeof(int));   // 10 MB
    int*  dcount = (int*)carve((size_t)NN * sizeof(int));
    int*  cursor = (int*)carve((size_t)NN * sizeof(int));
    int*  doff   = (int*)carve((size_t)NN * sizeof(int));
    int*  bsum   = (int*)carve(256 * sizeof(int));
    int4* epack  = (int4*)carve((size_t)EE * sizeof(int4));      // 16 MB
    __hip_bfloat16* h0 = (__hip_bfloat16*)carve((size_t)NN * DIN * 2);
    __hip_bfloat16* h1 = (__hip_bfloat16*)carve((size_t)NN * DIN * 2);
    __hip_bfloat16* h2 = (__hip_bfloat16*)carve((size_t)NN * DIN * 2);
    float* pre = (float*)carve((size_t)NN * 8 * sizeof(float));
    short* wt0 = (short*)carve((size_t)64 * KTOT * sizeof(short));
    short* wt1 = (short*)carve((size_t)64 * KTOT * sizeof(short));
    short* wt2 = (short*)carve((size_t)16 * KTOT * sizeof(short));
    float* cp0 = (float*)carve((size_t)RR * CPAD * sizeof(float));
    float* cp1 = (float*)carve((size_t)RR * CPAD * sizeof(float));
    float* cp2 = (float*)carve((size_t)RR * CPAD * sizeof(float));

    // cnt, dcount, cursor are adjacent in the carve order -> one memset
    hipMemsetAsync(cnt, 0, (size_t)NN * (RR + 2) * sizeof(int) + 512, stream);

    const int EB = (EE + 255) / 256;   // 3907
    const int NB = (NN + 255) / 256;   // 196
    k_hist<<<EB, 256, 0, stream>>>(dstp, etype, cnt, dcount);
    k_scan1<<<NB, 256, 0, stream>>>(dcount, doff, bsum);
    k_scan2<<<1, 256, 0, stream>>>(bsum, NB);
    k_scan3<<<NB, 256, 0, stream>>>(doff, bsum);
    k_scatter<<<EB, 256, 0, stream>>>(srcp, dstp, etype, cnt, doff, cursor, epack);
    k_cast_x<<<(NN * DIN + 255) / 256, 256, 0, stream>>>(x, h0);
    k_prep_comp<<<(RR * CPAD + 255) / 256, 256, 0, stream>>>(comp0, cp0);
    k_prep_comp<<<(RR * CPAD + 255) / 256, 256, 0, stream>>>(comp1, cp1);
    k_prep_comp<<<(RR * CPAD + 255) / 256, 256, 0, stream>>>(comp2, cp2);
    k_prep_w<<<(64 * KTOT + 255) / 256, 256, 0, stream>>>(bases0, root0, wt0, 64, 64);
    k_prep_w<<<(64 * KTOT + 255) / 256, 256, 0, stream>>>(bases1, root1, wt1, 64, 64);
    k_prep_w<<<(16 * KTOT + 255) / 256, 256, 0, stream>>>(bases2, root2, wt2, 8, 16);

    const int NF = (NN + NBW - 1) / NBW;   // 3125
    k_fused<64, true ><<<NF, 512, 0, stream>>>(h0, epack, doff, dcount, cp0, wt0, bias0, (void*)h1);
    k_fused<64, true ><<<NF, 512, 0, stream>>>(h1, epack, doff, dcount, cp1, wt1, bias1, (void*)h2);
    k_fused<8,  false><<<NF, 512, 0, stream>>>(h2, epack, doff, dcount, cp2, wt2, bias2, (void*)pre);
    k_lsm<<<NB, 256, 0, stream>>>(pre, (float*)d_out);
}